// Round 4
// baseline (467.974 us; speedup 1.0000x reference)
//
#include <hip/hip_runtime.h>
#include <hip/hip_fp16.h>

typedef __attribute__((ext_vector_type(2))) int i32x2;

#define HH 1024
#define ROWP 512                   // pixel-pairs per row
#define NBLK 256                   // 1 block/CU -> co-resident
#define TPB 512
#define NSYNC 25                   // 4 Jacobi steps per sync (4-row halo)
#define BOUNDARY_F 0.1f
#define TOKEN 0x5A5A5A5Au
#define FLAGS_N (NSYNC * NBLK)

union h2u { __half2 h; int i; };

__device__ __forceinline__ i32x2 pack4(float4 v) {     // fp32x4 -> fp16x4 (RNE)
    h2u a, b;
    a.h = __float22half2_rn(make_float2(v.x, v.y));
    b.h = __float22half2_rn(make_float2(v.z, v.w));
    i32x2 r; r.x = a.i; r.y = b.i;
    return r;
}
__device__ __forceinline__ float4 unpack4(i32x2 p) {
    h2u a, b; a.i = p.x; b.i = p.y;
    float2 lo = __half22float2(a.h);
    float2 hi = __half22float2(b.h);
    return make_float4(lo.x, lo.y, hi.x, hi.y);
}
__device__ __forceinline__ unsigned packh2(float a, float b) {
    h2u u; u.h = __float22half2_rn(make_float2(a, b));
    return (unsigned)u.i;
}
__device__ __forceinline__ float2 uph2(unsigned u) {
    h2u x; x.i = (int)u; return __half22float2(x.h);
}

// coherent 8B store: single fabric transaction, bypasses non-coherent L2
__device__ __forceinline__ void cst8(i32x2* base, int elem, i32x2 val) {
    asm volatile("global_store_dwordx2 %0, %1, %2 sc0 sc1"
                 :: "v"(elem * 8), "v"(val), "s"(base) : "memory");
}
// coherent 8B load; result MUST be passed through wait8 before any use
__device__ __forceinline__ i32x2 cld8(const i32x2* base, int elem) {
    i32x2 t;
    asm volatile("global_load_dwordx2 %0, %1, %2 sc0 sc1"
                 : "=v"(t) : "v"(elem * 8), "s"(base) : "memory");
    return t;
}
// s_waitcnt with loaded registers as in/out operands: all later uses have a
// data dependency THROUGH the waitcnt (round-12-verified hazard fix).
__device__ __forceinline__ void wait8(i32x2& a, i32x2& b, i32x2& c, i32x2& d,
                                      i32x2& e, i32x2& f, i32x2& g, i32x2& h) {
    asm volatile("s_waitcnt vmcnt(0)"
                 : "+v"(a), "+v"(b), "+v"(c), "+v"(d),
                   "+v"(e), "+v"(f), "+v"(g), "+v"(h) :: "memory");
}
__device__ __forceinline__ void waitvm0() {
    asm volatile("s_waitcnt vmcnt(0)" ::: "memory");
}

__device__ __forceinline__ float wfun(float c, float n, float valid) {
    float same = ((c > BOUNDARY_F) != (n > BOUNDARY_F)) ? 1.0f : 0.0f;
    return valid * __expf(-fabsf(c - n + same));
}

// Jacobi update of one pixel-pair from packed fp16 weights.
// cwr[0]={w0u,w0d}, cwr[1]={w0l,w1r}, cwr[2]={w1u,w1d}; the pair-internal
// weights are DERIVED in fp32 (w0r = 1-w0u-w0d-w0l, w1l = 1-w1u-w1d-w1r) so
// each row sums to exactly 1.0 -> no multiplicative drift over 100 iters.
// (Derived weights are never the boundary-zeroed ones: pair-internal links
// are always valid, and valid=0 weights quantize to exact fp16 zeros.)
__device__ __forceinline__ float4 stepw(const unsigned* cwr, bool m0, bool m1,
                                        float4 xc, float4 xu, float4 xd,
                                        float2 xl, float2 xr) {
    float2 ud0 = uph2(cwr[0]);           // w0u, w0d
    float2 lr  = uph2(cwr[1]);           // w0l, w1r
    float2 ud1 = uph2(cwr[2]);           // w1u, w1d
    float w0r = 1.0f - ud0.x - ud0.y - lr.x;
    float w1l = 1.0f - ud1.x - ud1.y - lr.y;
    float4 o;
    o.x = ud0.x*xu.x + ud0.y*xd.x + lr.x*xl.x + w0r*xc.z;
    o.y = ud0.x*xu.y + ud0.y*xd.y + lr.x*xl.y + w0r*xc.w;
    o.z = ud1.x*xu.z + ud1.y*xd.z + w1l*xc.x + lr.y*xr.x;
    o.w = ud1.x*xu.w + ud1.y*xd.w + w1l*xc.y + lr.y*xr.y;
    if (m0) { o.x = xc.x; o.y = xc.y; }     // absorbing seeds
    if (m1) { o.z = xc.z; o.w = xc.w; }
    return o;
}

__device__ __forceinline__ void horiz(const float4* row, int tid, float4 xc,
                                      float2* xl, float2* xr) {
    const float2* r2 = (const float2*)row;
    *xl = (tid > 0) ? r2[2 * tid - 1] : make_float2(xc.x, xc.y);
    *xr = (tid < ROWP - 1) ? r2[2 * tid + 2] : make_float2(xc.z, xc.w);
}

// zero all flag slots: every launch self-contained (round-16-verified fix)
__global__ void rw_init_kernel(unsigned* __restrict__ flags) {
    int g = blockIdx.x * blockDim.x + threadIdx.x;
    if (g < FLAGS_N) flags[g] = 0u;
}

// Wavefront (diagonal) schedule: group r computes {y1[r], y2[r-1], y3[r-2],
// y4[r-3]} so each level's rows die one group after creation. Peak register
// liveness ~110 (cw 30 + shrinking x0 + three 3-row windows) -- fits under
// the immovable 128-VGPR cap (rounds 1-3: allocator pegs 128 and spills the
// level-major k=4 schedule's ~168-live state onto the barrier chain).
// Verticals stay in registers (same thread); only horiz goes through LDS.
__launch_bounds__(TPB)
__global__ void rw_persist_kernel(const float* __restrict__ img,
                                  const int* __restrict__ seeds,
                                  float4* __restrict__ out4,   // d_out fp32, final only
                                  i32x2* __restrict__ parE,    // ws: fp16 x_{4m}, m even
                                  i32x2* __restrict__ parO,    // ws: fp16 x_{4m}, m odd
                                  unsigned* __restrict__ flags) {
    const int tid = threadIdx.x;
    const int blk = blockIdx.x;
    const int band = ((blk & 7) << 5) | (blk >> 3);   // XCD swizzle (perf only)
    const int i0 = band * 4;

    // Working rows L=0..11 <-> global row i0-4+L. Own rows L=4..7.
    // X[s] = x0 row s+1 horiz copy (rows 1..10). R1/R2/R3: 3-slot rotating
    // rings for y1/y2/y3 horiz (write@group r, read@r+1, rewrite@r+3 -- one
    // full barrier between last read and rewrite).
    __shared__ float4 X [10][ROWP];                   // 80 KB
    __shared__ float4 R1[3][ROWP];                    // 24 KB
    __shared__ float4 R2[3][ROWP];                    // 24 KB
    __shared__ float4 R3[3][ROWP];                    // 24 KB  (total 152 KB)

    // ---- iteration-invariant packed weights + masks for rows L=1..10 ----
    unsigned cw[10][3];                               // 30 VGPRs (was 80 fp32)
    unsigned mb0 = 0, mb1 = 0;
    float4 xr4, xr5, xr6, xr7;                        // own rows (persistent)
    {
        const float2* img2 = (const float2*)img;
        const int2* seeds2 = (const int2*)seeds;
#pragma unroll
        for (int L = 1; L <= 10; ++L) {
            const int g = min(max(i0 - 4 + L, 0), HH - 1);
            const int P = g * ROWP + tid;
            const int p = P * 2;
            const int j = p & 1023;
            const int uP = (g > 0) ? P - ROWP : P;
            const int dP = (g < HH - 1) ? P + ROWP : P;
            const int lp = (j > 0) ? p - 1 : p;
            const int rp = (j < 1022) ? p + 2 : p + 1;

            float2 cc = img2[P], iu = img2[uP], id = img2[dP];
            float il = img[lp], ir = img[rp];
            const float vU = (g > 0) ? 1.0f : 0.0f;
            const float vD = (g < HH - 1) ? 1.0f : 0.0f;
            const float vL = (j > 0) ? 1.0f : 0.0f;
            const float vR = (j < 1022) ? 1.0f : 0.0f;

            float w0u = wfun(cc.x, iu.x, vU), w0d = wfun(cc.x, id.x, vD);
            float w0l = wfun(cc.x, il, vL),   w0r = wfun(cc.x, cc.y, 1.0f);
            float rs0 = w0u + w0d + w0l + w0r;
            float inv0 = (rs0 > 0.0f) ? 1.0f / rs0 : 0.0f;
            float w1u = wfun(cc.y, iu.y, vU), w1d = wfun(cc.y, id.y, vD);
            float w1l = wfun(cc.y, cc.x, 1.0f), w1r = wfun(cc.y, ir, vR);
            float rs1 = w1u + w1d + w1l + w1r;
            float inv1 = (rs1 > 0.0f) ? 1.0f / rs1 : 0.0f;

            cw[L-1][0] = packh2(w0u * inv0, w0d * inv0);
            cw[L-1][1] = packh2(w0l * inv0, w1r * inv1);
            cw[L-1][2] = packh2(w1u * inv1, w1d * inv1);

            int2 s = seeds2[P];
            if (s.x > 0) mb0 |= 1u << L;
            if (s.y > 0) mb1 |= 1u << L;
            if (L >= 4 && L <= 7) {
                float4 v;
                v.x = (s.x == 1) ? 1.0f : 0.0f;
                v.y = (s.x == 2) ? 1.0f : 0.0f;
                v.z = (s.y == 1) ? 1.0f : 0.0f;
                v.w = (s.y == 2) ? 1.0f : 0.0f;
                if (L == 4) xr4 = v; else if (L == 5) xr5 = v;
                else if (L == 6) xr6 = v; else xr7 = v;
            }
        }
    }

    // ---- publish x0 (fp16) -> parE + seed LDS horizontal copies ----
    X[3][tid] = xr4; X[4][tid] = xr5;
    X[5][tid] = xr6; X[6][tid] = xr7;
    cst8(parE, (i0 + 0) * ROWP + tid, pack4(xr4));
    cst8(parE, (i0 + 1) * ROWP + tid, pack4(xr5));
    cst8(parE, (i0 + 2) * ROWP + tid, pack4(xr6));
    cst8(parE, (i0 + 3) * ROWP + tid, pack4(xr7));
    waitvm0();
    __syncthreads();               // LDS visible + publish drained
    if (tid == 0)
        __hip_atomic_store(&flags[band], TOKEN, __ATOMIC_RELAXED,
                           __HIP_MEMORY_SCOPE_AGENT);

    // ghost global rows (clamped; clamped rows get weight 0 on the real rows)
    const int gU0 = max(i0 - 4, 0), gU1 = max(i0 - 3, 0);
    const int gU2 = max(i0 - 2, 0), gU3 = max(i0 - 1, 0);
    const int gD0 = min(i0 + 4, HH - 1), gD1 = min(i0 + 5, HH - 1);
    const int gD2 = min(i0 + 6, HH - 1), gD3 = min(i0 + 7, HH - 1);

    // update with horiz from LDS slot; verticals/center from registers
#define HUPD(dst, CWI, BIT, xc_, xu_, xd_, SLOT) do {                        \
        float2 xl_, xr_;                                                     \
        horiz(&SLOT[0], tid, xc_, &xl_, &xr_);                               \
        dst = stepw(cw[CWI], (mb0 >> (BIT)) & 1, (mb1 >> (BIT)) & 1,         \
                    xc_, xu_, xd_, xl_, xr_);                                \
    } while (0)

    for (int m = 0; m < NSYNC; ++m) {
        // ---- poll neighbors' x_{4m} flags (two waves in parallel) ----
        if (tid == 0 && band > 0) {
            int guard = 0;
            while (__hip_atomic_load(&flags[m * NBLK + band - 1], __ATOMIC_RELAXED,
                                     __HIP_MEMORY_SCOPE_AGENT) != TOKEN) {
                if (++guard > (1 << 22)) break;
            }
        }
        if (tid == 64 && band < NBLK - 1) {
            int guard = 0;
            while (__hip_atomic_load(&flags[m * NBLK + band + 1], __ATOMIC_RELAXED,
                                     __HIP_MEMORY_SCOPE_AGENT) != TOKEN) {
                if (++guard > (1 << 22)) break;
            }
        }
        __syncthreads();                              // [A]
        asm volatile("" ::: "memory");

        const i32x2* pin = (m & 1) ? parO : parE;

        // ---- issue 4-deep ghost row loads (coherent fp16 8B) ----
        i32x2 rA = cld8(pin, gU0 * ROWP + tid);       // L=0
        i32x2 rB = cld8(pin, gU1 * ROWP + tid);       // L=1
        i32x2 rC = cld8(pin, gU2 * ROWP + tid);       // L=2
        i32x2 rD = cld8(pin, gU3 * ROWP + tid);       // L=3
        i32x2 rE = cld8(pin, gD0 * ROWP + tid);       // L=8
        i32x2 rF = cld8(pin, gD1 * ROWP + tid);       // L=9
        i32x2 rG = cld8(pin, gD2 * ROWP + tid);       // L=10
        i32x2 rH = cld8(pin, gD3 * ROWP + tid);       // L=11

        // ---- y1 rows 5,6 need no ghosts: compute while loads fly ----
        float4 y1_5, y1_6;
        HUPD(y1_5, 4, 5, xr5, xr4, xr6, X[4]);
        HUPD(y1_6, 5, 6, xr6, xr5, xr7, X[5]);

        wait8(rA, rB, rC, rD, rE, rF, rG, rH);        // loads landed; deps tied
        float4 xr0  = unpack4(rA);
        float4 xr1  = unpack4(rB);
        float4 xr2  = unpack4(rC);
        float4 xr3  = unpack4(rD);
        float4 xr8  = unpack4(rE);
        float4 xr9  = unpack4(rF);
        float4 xr10 = unpack4(rG);
        float4 xr11 = unpack4(rH);
        X[0][tid] = xr1; X[1][tid] = xr2; X[2][tid] = xr3;
        X[7][tid] = xr8; X[8][tid] = xr9; X[9][tid] = xr10;
        __syncthreads();                              // [B]

        // ---- wavefront groups; barrier between groups covers LDS w->r ----
        float4 y1_1, y1_2, y1_3, y1_4, y1_7, y1_8, y1_9, y1_10;
        float4 y2_2, y2_3, y2_4, y2_5, y2_6, y2_7, y2_8, y2_9;
        float4 y3_3, y3_4, y3_5, y3_6, y3_7, y3_8;
        float4 o0, o1, o2, o3;

        // group 1 (no LDS writes -> no barrier)
        HUPD(y1_1, 0, 1, xr1, xr0, xr2, X[0]);
        // group 2
        HUPD(y1_2, 1, 2, xr2, xr1, xr3, X[1]);
        R1[2][tid] = y1_2;
        __syncthreads();
        // group 3
        HUPD(y1_3, 2, 3, xr3, xr2, xr4, X[2]);
        HUPD(y2_2, 1, 2, y1_2, y1_1, y1_3, R1[2]);
        R1[0][tid] = y1_3;
        __syncthreads();
        // group 4
        HUPD(y1_4, 3, 4, xr4, xr3, xr5, X[3]);
        HUPD(y2_3, 2, 3, y1_3, y1_2, y1_4, R1[0]);
        R1[1][tid] = y1_4; R2[0][tid] = y2_3;
        __syncthreads();
        // group 5 (y1_5 precomputed)
        HUPD(y2_4, 3, 4, y1_4, y1_3, y1_5, R1[1]);
        HUPD(y3_3, 2, 3, y2_3, y2_2, y2_4, R2[0]);
        R1[2][tid] = y1_5; R2[1][tid] = y2_4;
        __syncthreads();
        // group 6 (y1_6 precomputed)
        HUPD(y2_5, 4, 5, y1_5, y1_4, y1_6, R1[2]);
        HUPD(y3_4, 3, 4, y2_4, y2_3, y2_5, R2[1]);
        R1[0][tid] = y1_6; R2[2][tid] = y2_5; R3[1][tid] = y3_4;
        __syncthreads();
        // group 7
        HUPD(y1_7, 6, 7, xr7, xr6, xr8, X[6]);
        HUPD(y2_6, 5, 6, y1_6, y1_5, y1_7, R1[0]);
        HUPD(y3_5, 4, 5, y2_5, y2_4, y2_6, R2[2]);
        HUPD(o0,   3, 4, y3_4, y3_3, y3_5, R3[1]);
        R1[1][tid] = y1_7; R2[0][tid] = y2_6; R3[2][tid] = y3_5;
        __syncthreads();
        // group 8
        HUPD(y1_8, 7, 8, xr8, xr7, xr9, X[7]);
        HUPD(y2_7, 6, 7, y1_7, y1_6, y1_8, R1[1]);
        HUPD(y3_6, 5, 6, y2_6, y2_5, y2_7, R2[0]);
        HUPD(o1,   4, 5, y3_5, y3_4, y3_6, R3[2]);
        R1[2][tid] = y1_8; R2[1][tid] = y2_7; R3[0][tid] = y3_6;
        __syncthreads();
        // group 9
        HUPD(y1_9, 8, 9, xr9, xr8, xr10, X[8]);
        HUPD(y2_8, 7, 8, y1_8, y1_7, y1_9, R1[2]);
        HUPD(y3_7, 6, 7, y2_7, y2_6, y2_8, R2[1]);
        HUPD(o2,   5, 6, y3_6, y3_5, y3_7, R3[0]);
        R1[0][tid] = y1_9; R2[2][tid] = y2_8; R3[1][tid] = y3_7;
        __syncthreads();
        // group 10 (last rows of each level: no LDS writes needed)
        HUPD(y1_10, 9, 10, xr10, xr9, xr11, X[9]);
        HUPD(y2_9, 8, 9, y1_9, y1_8, y1_10, R1[0]);
        HUPD(y3_8, 7, 8, y2_8, y2_7, y2_9, R2[2]);
        HUPD(o3,   6, 7, y3_7, y3_6, y3_8, R3[1]);

        if (m == NSYNC - 1) {
            // x_100 -> d_out fp32 (never read by any block: race-free)
            out4[(i0 + 0) * ROWP + tid] = o0;
            out4[(i0 + 1) * ROWP + tid] = o1;
            out4[(i0 + 2) * ROWP + tid] = o2;
            out4[(i0 + 3) * ROWP + tid] = o3;
            break;
        }

        // ---- publish own rows (after group 10: no in-loop store drains) ----
        i32x2* pout = (m & 1) ? parE : parO;
        cst8(pout, (i0 + 0) * ROWP + tid, pack4(o0));
        cst8(pout, (i0 + 1) * ROWP + tid, pack4(o1));
        cst8(pout, (i0 + 2) * ROWP + tid, pack4(o2));
        cst8(pout, (i0 + 3) * ROWP + tid, pack4(o3));
        waitvm0();                                    // each wave drains publishes
        __syncthreads();                              // [D] all waves drained
        if (tid == 0)
            __hip_atomic_store(&flags[(m + 1) * NBLK + band], TOKEN,
                               __ATOMIC_RELAXED, __HIP_MEMORY_SCOPE_AGENT);

        // ---- off-chain: LDS writeback + register rotation (hidden under the
        // neighbors' poll window; made visible by next sync's [A] barrier) ----
        X[3][tid] = o0; X[4][tid] = o1;
        X[5][tid] = o2; X[6][tid] = o3;
        xr4 = o0; xr5 = o1; xr6 = o2; xr7 = o3;
    }
#undef HUPD
}

extern "C" void kernel_launch(void* const* d_in, const int* in_sizes, int n_in,
                              void* d_out, int out_size, void* d_ws, size_t ws_size,
                              hipStream_t stream) {
    const float* img = (const float*)d_in[0];
    const int* seeds = (const int*)d_in[1];

    float4* out4 = (float4*)d_out;                              // fp32 final only
    char* ws = (char*)d_ws;
    i32x2* parE = (i32x2*)ws;                                   // 4 MB fp16 even parity
    i32x2* parO = (i32x2*)(ws + 4ull * 1024 * 1024);            // 4 MB fp16 odd parity
    unsigned* flags = (unsigned*)(ws + 8ull * 1024 * 1024);     // 25.6 KB token slots

    rw_init_kernel<<<(FLAGS_N + 255) / 256, 256, 0, stream>>>(flags);
    rw_persist_kernel<<<NBLK, TPB, 0, stream>>>(img, seeds, out4, parE, parO, flags);
}

// Round 5
// 365.170 us; speedup vs baseline: 1.2815x; 1.2815x over previous
//
#include <hip/hip_runtime.h>
#include <hip/hip_fp16.h>

typedef __attribute__((ext_vector_type(2))) int i32x2;

#define HH 1024
#define ROWP 512                   // pixel-pairs per row
#define NBLK 256                   // 1 block/CU -> co-resident
#define TPB 512
#define NSYNC 25                   // 4 Jacobi steps per sync (4-row halo)
#define BOUNDARY_F 0.1f
#define TOKEN 0x5A5A5A5Au
#define FLAGS_N (NSYNC * NBLK)

union h2u { __half2 h; int i; };

__device__ __forceinline__ i32x2 pack4(float4 v) {     // fp32x4 -> fp16x4 (RNE)
    h2u a, b;
    a.h = __float22half2_rn(make_float2(v.x, v.y));
    b.h = __float22half2_rn(make_float2(v.z, v.w));
    i32x2 r; r.x = a.i; r.y = b.i;
    return r;
}
__device__ __forceinline__ float4 unpack4(i32x2 p) {
    h2u a, b; a.i = p.x; b.i = p.y;
    float2 lo = __half22float2(a.h);
    float2 hi = __half22float2(b.h);
    return make_float4(lo.x, lo.y, hi.x, hi.y);
}
__device__ __forceinline__ unsigned packh2(float a, float b) {
    h2u u; u.h = __float22half2_rn(make_float2(a, b));
    return (unsigned)u.i;
}
__device__ __forceinline__ float2 uph2(unsigned u) {
    h2u x; x.i = (int)u; return __half22float2(x.h);
}

// coherent 8B store: single fabric transaction, bypasses non-coherent L2
__device__ __forceinline__ void cst8(i32x2* base, int elem, i32x2 val) {
    asm volatile("global_store_dwordx2 %0, %1, %2 sc0 sc1"
                 :: "v"(elem * 8), "v"(val), "s"(base) : "memory");
}
// coherent 8B load; result MUST be passed through wait8 before any use
__device__ __forceinline__ i32x2 cld8(const i32x2* base, int elem) {
    i32x2 t;
    asm volatile("global_load_dwordx2 %0, %1, %2 sc0 sc1"
                 : "=v"(t) : "v"(elem * 8), "s"(base) : "memory");
    return t;
}
// s_waitcnt with loaded registers as in/out operands: all later uses have a
// data dependency THROUGH the waitcnt (round-12-verified hazard fix).
__device__ __forceinline__ void wait8(i32x2& a, i32x2& b, i32x2& c, i32x2& d,
                                      i32x2& e, i32x2& f, i32x2& g, i32x2& h) {
    asm volatile("s_waitcnt vmcnt(0)"
                 : "+v"(a), "+v"(b), "+v"(c), "+v"(d),
                   "+v"(e), "+v"(f), "+v"(g), "+v"(h) :: "memory");
}
__device__ __forceinline__ void waitvm0() {
    asm volatile("s_waitcnt vmcnt(0)" ::: "memory");
}

__device__ __forceinline__ float wfun(float c, float n, float valid) {
    float same = ((c > BOUNDARY_F) != (n > BOUNDARY_F)) ? 1.0f : 0.0f;
    return valid * __expf(-fabsf(c - n + same));
}

// Jacobi update of one pixel-pair from packed fp16 weights (round-4-verified
// numerics: absmax unchanged). cwr[0]={w0u,w0d}, cwr[1]={w0l,w1r},
// cwr[2]={w1u,w1d}; pair-internal weights DERIVED in fp32
// (w0r = 1-w0u-w0d-w0l, w1l = 1-w1u-w1d-w1r) so each row sums to exactly
// 1.0 -> no multiplicative drift over 100 iters. Derived weights are never
// the boundary-zeroed ones (pair-internal links always valid); valid=0
// weights quantize to exact fp16 zeros. Saves 50 VGPRs vs fp32 cfv[10][8],
// which is what lets the k=4 level-major schedule fit the 128-VGPR ceiling
// the allocator pegs regardless of launch_bounds/waves_per_eu (rounds 1-3).
__device__ __forceinline__ float4 stepw(const unsigned* cwr, bool m0, bool m1,
                                        float4 xc, float4 xu, float4 xd,
                                        float2 xl, float2 xr) {
    float2 ud0 = uph2(cwr[0]);           // w0u, w0d
    float2 lr  = uph2(cwr[1]);           // w0l, w1r
    float2 ud1 = uph2(cwr[2]);           // w1u, w1d
    float w0r = 1.0f - ud0.x - ud0.y - lr.x;
    float w1l = 1.0f - ud1.x - ud1.y - lr.y;
    float4 o;
    o.x = ud0.x*xu.x + ud0.y*xd.x + lr.x*xl.x + w0r*xc.z;
    o.y = ud0.x*xu.y + ud0.y*xd.y + lr.x*xl.y + w0r*xc.w;
    o.z = ud1.x*xu.z + ud1.y*xd.z + w1l*xc.x + lr.y*xr.x;
    o.w = ud1.x*xu.w + ud1.y*xd.w + w1l*xc.y + lr.y*xr.y;
    if (m0) { o.x = xc.x; o.y = xc.y; }     // absorbing seeds
    if (m1) { o.z = xc.z; o.w = xc.w; }
    return o;
}

__device__ __forceinline__ void horiz(const float4* row, int tid, float4 xc,
                                      float2* xl, float2* xr) {
    const float2* r2 = (const float2*)row;
    *xl = (tid > 0) ? r2[2 * tid - 1] : make_float2(xc.x, xc.y);
    *xr = (tid < ROWP - 1) ? r2[2 * tid + 2] : make_float2(xc.z, xc.w);
}

// zero all flag slots: every launch self-contained (round-16-verified fix)
__global__ void rw_init_kernel(unsigned* __restrict__ flags) {
    int g = blockIdx.x * blockDim.x + threadIdx.x;
    if (g < FLAGS_N) flags[g] = 0u;
}

// Level-major k=4 schedule (rounds 1-3 structure: 6 barriers/sync) with
// packed-fp16 weights (round-4-verified numerics). Peak liveness at step-1:
// cw 30 + ghost x0 32 + own 16 + y1-in-flight <=40 (x0 dies as y1 grows)
// ~= 115-120 < 128 -> no scratch spill under the allocator's 128 ceiling.
// Rounds 1-3 (fp32 cfv, ~168 live) spilled ~27 MB onto the barrier chain.
__launch_bounds__(TPB)
__global__ void rw_persist_kernel(const float* __restrict__ img,
                                  const int* __restrict__ seeds,
                                  float4* __restrict__ out4,   // d_out fp32, final only
                                  i32x2* __restrict__ parE,    // ws: fp16 x_{4m}, m even
                                  i32x2* __restrict__ parO,    // ws: fp16 x_{4m}, m odd
                                  unsigned* __restrict__ flags) {
    const int tid = threadIdx.x;
    const int blk = blockIdx.x;
    const int band = ((blk & 7) << 5) | (blk >> 3);   // XCD swizzle (perf only)
    const int i0 = band * 4;

    // Working rows L=0..11 <-> global row i0-4+L. Own rows L=4..7.
    // bufA: x^0 rows L=1..10 at slot L-1 (step-1 horiz); later y2 rows L=3..8 at slot L-3
    // bufB: y1 rows L=2..9 at slot L-2;                  later y3 rows L=4..7 at slot L-4
    __shared__ float4 bufA[10][ROWP];                 // 80 KB
    __shared__ float4 bufB[8][ROWP];                  // 64 KB (total 144 KB <= 160 KB/CU)

    // ---- iteration-invariant packed weights + masks for rows L=1..10 ----
    unsigned cw[10][3];                               // 30 VGPRs (was 80 fp32)
    unsigned mb0 = 0, mb1 = 0;
    float4 s0, s1, s2, s3;                            // register-resident band (fp32)
    {
        const float2* img2 = (const float2*)img;
        const int2* seeds2 = (const int2*)seeds;
#pragma unroll
        for (int L = 1; L <= 10; ++L) {
            const int g = min(max(i0 - 4 + L, 0), HH - 1);
            const int P = g * ROWP + tid;
            const int p = P * 2;
            const int j = p & 1023;
            const int uP = (g > 0) ? P - ROWP : P;
            const int dP = (g < HH - 1) ? P + ROWP : P;
            const int lp = (j > 0) ? p - 1 : p;
            const int rp = (j < 1022) ? p + 2 : p + 1;

            float2 cc = img2[P], iu = img2[uP], id = img2[dP];
            float il = img[lp], ir = img[rp];
            const float vU = (g > 0) ? 1.0f : 0.0f;
            const float vD = (g < HH - 1) ? 1.0f : 0.0f;
            const float vL = (j > 0) ? 1.0f : 0.0f;
            const float vR = (j < 1022) ? 1.0f : 0.0f;

            float w0u = wfun(cc.x, iu.x, vU), w0d = wfun(cc.x, id.x, vD);
            float w0l = wfun(cc.x, il, vL),   w0r = wfun(cc.x, cc.y, 1.0f);
            float rs0 = w0u + w0d + w0l + w0r;
            float inv0 = (rs0 > 0.0f) ? 1.0f / rs0 : 0.0f;
            float w1u = wfun(cc.y, iu.y, vU), w1d = wfun(cc.y, id.y, vD);
            float w1l = wfun(cc.y, cc.x, 1.0f), w1r = wfun(cc.y, ir, vR);
            float rs1 = w1u + w1d + w1l + w1r;
            float inv1 = (rs1 > 0.0f) ? 1.0f / rs1 : 0.0f;

            cw[L-1][0] = packh2(w0u * inv0, w0d * inv0);
            cw[L-1][1] = packh2(w0l * inv0, w1r * inv1);
            cw[L-1][2] = packh2(w1u * inv1, w1d * inv1);

            int2 s = seeds2[P];
            if (s.x > 0) mb0 |= 1u << L;
            if (s.y > 0) mb1 |= 1u << L;
            if (L >= 4 && L <= 7) {
                float4 v;
                v.x = (s.x == 1) ? 1.0f : 0.0f;
                v.y = (s.x == 2) ? 1.0f : 0.0f;
                v.z = (s.y == 1) ? 1.0f : 0.0f;
                v.w = (s.y == 2) ? 1.0f : 0.0f;
                if (L == 4) s0 = v; else if (L == 5) s1 = v;
                else if (L == 6) s2 = v; else s3 = v;
            }
        }
    }

    // ---- publish x0 (fp16) -> parE + seed LDS horizontal copies ----
    bufA[3][tid] = s0; bufA[4][tid] = s1;
    bufA[5][tid] = s2; bufA[6][tid] = s3;
    cst8(parE, (i0 + 0) * ROWP + tid, pack4(s0));
    cst8(parE, (i0 + 1) * ROWP + tid, pack4(s1));
    cst8(parE, (i0 + 2) * ROWP + tid, pack4(s2));
    cst8(parE, (i0 + 3) * ROWP + tid, pack4(s3));
    waitvm0();
    __syncthreads();               // LDS visible + publish drained
    if (tid == 0)
        __hip_atomic_store(&flags[band], TOKEN, __ATOMIC_RELAXED,
                           __HIP_MEMORY_SCOPE_AGENT);

    // ghost global rows (clamped; clamped rows get weight 0 on the real rows)
    const int gU0 = max(i0 - 4, 0), gU1 = max(i0 - 3, 0);
    const int gU2 = max(i0 - 2, 0), gU3 = max(i0 - 1, 0);
    const int gD0 = min(i0 + 4, HH - 1), gD1 = min(i0 + 5, HH - 1);
    const int gD2 = min(i0 + 6, HH - 1), gD3 = min(i0 + 7, HH - 1);

    for (int m = 0; m < NSYNC; ++m) {
        // ---- poll neighbors' x_{4m} flags (two waves in parallel; 4-row halo
        // comes entirely from the distance-1 band, so topology unchanged) ----
        if (tid == 0 && band > 0) {
            int guard = 0;
            while (__hip_atomic_load(&flags[m * NBLK + band - 1], __ATOMIC_RELAXED,
                                     __HIP_MEMORY_SCOPE_AGENT) != TOKEN) {
                if (++guard > (1 << 22)) break;
            }
        }
        if (tid == 64 && band < NBLK - 1) {
            int guard = 0;
            while (__hip_atomic_load(&flags[m * NBLK + band + 1], __ATOMIC_RELAXED,
                                     __HIP_MEMORY_SCOPE_AGENT) != TOKEN) {
                if (++guard > (1 << 22)) break;
            }
        }
        __syncthreads();                              // [A]
        asm volatile("" ::: "memory");

        const i32x2* pin = (m & 1) ? parO : parE;

        // ---- issue 4-deep ghost row loads (coherent fp16 8B) ----
        i32x2 rA = cld8(pin, gU0 * ROWP + tid);       // L=0
        i32x2 rB = cld8(pin, gU1 * ROWP + tid);       // L=1
        i32x2 rC = cld8(pin, gU2 * ROWP + tid);       // L=2
        i32x2 rD = cld8(pin, gU3 * ROWP + tid);       // L=3
        i32x2 rE = cld8(pin, gD0 * ROWP + tid);       // L=8
        i32x2 rF = cld8(pin, gD1 * ROWP + tid);       // L=9
        i32x2 rG = cld8(pin, gD2 * ROWP + tid);       // L=10
        i32x2 rH = cld8(pin, gD3 * ROWP + tid);       // L=11

        // ---- step 1 interior rows L=5,6 (no ghost dep) while loads fly ----
        float2 xl, xr;
        horiz(&bufA[4][0], tid, s1, &xl, &xr);
        float4 y1_5 = stepw(cw[4], (mb0 >> 5) & 1, (mb1 >> 5) & 1, s1, s0, s2, xl, xr);
        horiz(&bufA[5][0], tid, s2, &xl, &xr);
        float4 y1_6 = stepw(cw[5], (mb0 >> 6) & 1, (mb1 >> 6) & 1, s2, s1, s3, xl, xr);
        bufB[3][tid] = y1_5;
        bufB[4][tid] = y1_6;

        wait8(rA, rB, rC, rD, rE, rF, rG, rH);        // loads landed; deps tied
        float4 x0_0  = unpack4(rA);
        float4 x0_1  = unpack4(rB);
        float4 x0_2  = unpack4(rC);
        float4 x0_3  = unpack4(rD);
        float4 x0_8  = unpack4(rE);
        float4 x0_9  = unpack4(rF);
        float4 x0_10 = unpack4(rG);
        float4 x0_11 = unpack4(rH);
        bufA[0][tid] = x0_1; bufA[1][tid] = x0_2; bufA[2][tid] = x0_3;
        bufA[7][tid] = x0_8; bufA[8][tid] = x0_9; bufA[9][tid] = x0_10;
        __syncthreads();                              // [B]

        // ---- step 1 ghost-dependent rows L=1..4, 7..10 ----
        horiz(&bufA[0][0], tid, x0_1, &xl, &xr);
        float4 y1_1 = stepw(cw[0], (mb0 >> 1) & 1, (mb1 >> 1) & 1, x0_1, x0_0, x0_2, xl, xr);
        horiz(&bufA[1][0], tid, x0_2, &xl, &xr);
        float4 y1_2 = stepw(cw[1], (mb0 >> 2) & 1, (mb1 >> 2) & 1, x0_2, x0_1, x0_3, xl, xr);
        horiz(&bufA[2][0], tid, x0_3, &xl, &xr);
        float4 y1_3 = stepw(cw[2], (mb0 >> 3) & 1, (mb1 >> 3) & 1, x0_3, x0_2, s0, xl, xr);
        horiz(&bufA[3][0], tid, s0, &xl, &xr);
        float4 y1_4 = stepw(cw[3], (mb0 >> 4) & 1, (mb1 >> 4) & 1, s0, x0_3, s1, xl, xr);
        horiz(&bufA[6][0], tid, s3, &xl, &xr);
        float4 y1_7 = stepw(cw[6], (mb0 >> 7) & 1, (mb1 >> 7) & 1, s3, s2, x0_8, xl, xr);
        horiz(&bufA[7][0], tid, x0_8, &xl, &xr);
        float4 y1_8 = stepw(cw[7], (mb0 >> 8) & 1, (mb1 >> 8) & 1, x0_8, s3, x0_9, xl, xr);
        horiz(&bufA[8][0], tid, x0_9, &xl, &xr);
        float4 y1_9 = stepw(cw[8], (mb0 >> 9) & 1, (mb1 >> 9) & 1, x0_9, x0_8, x0_10, xl, xr);
        horiz(&bufA[9][0], tid, x0_10, &xl, &xr);
        float4 y1_10 = stepw(cw[9], (mb0 >> 10) & 1, (mb1 >> 10) & 1, x0_10, x0_9, x0_11, xl, xr);
        bufB[0][tid] = y1_2; bufB[1][tid] = y1_3; bufB[2][tid] = y1_4;
        bufB[5][tid] = y1_7; bufB[6][tid] = y1_8; bufB[7][tid] = y1_9;
        __syncthreads();                              // [C1]

        // ---- step 2: rows L=2..9, vertical from regs, horiz bufB[L-2] ----
        horiz(&bufB[0][0], tid, y1_2, &xl, &xr);
        float4 y2_2 = stepw(cw[1], (mb0 >> 2) & 1, (mb1 >> 2) & 1, y1_2, y1_1, y1_3, xl, xr);
        horiz(&bufB[1][0], tid, y1_3, &xl, &xr);
        float4 y2_3 = stepw(cw[2], (mb0 >> 3) & 1, (mb1 >> 3) & 1, y1_3, y1_2, y1_4, xl, xr);
        horiz(&bufB[2][0], tid, y1_4, &xl, &xr);
        float4 y2_4 = stepw(cw[3], (mb0 >> 4) & 1, (mb1 >> 4) & 1, y1_4, y1_3, y1_5, xl, xr);
        horiz(&bufB[3][0], tid, y1_5, &xl, &xr);
        float4 y2_5 = stepw(cw[4], (mb0 >> 5) & 1, (mb1 >> 5) & 1, y1_5, y1_4, y1_6, xl, xr);
        horiz(&bufB[4][0], tid, y1_6, &xl, &xr);
        float4 y2_6 = stepw(cw[5], (mb0 >> 6) & 1, (mb1 >> 6) & 1, y1_6, y1_5, y1_7, xl, xr);
        horiz(&bufB[5][0], tid, y1_7, &xl, &xr);
        float4 y2_7 = stepw(cw[6], (mb0 >> 7) & 1, (mb1 >> 7) & 1, y1_7, y1_6, y1_8, xl, xr);
        horiz(&bufB[6][0], tid, y1_8, &xl, &xr);
        float4 y2_8 = stepw(cw[7], (mb0 >> 8) & 1, (mb1 >> 8) & 1, y1_8, y1_7, y1_9, xl, xr);
        horiz(&bufB[7][0], tid, y1_9, &xl, &xr);
        float4 y2_9 = stepw(cw[8], (mb0 >> 9) & 1, (mb1 >> 9) & 1, y1_9, y1_8, y1_10, xl, xr);
        bufA[0][tid] = y2_3; bufA[1][tid] = y2_4; bufA[2][tid] = y2_5;
        bufA[3][tid] = y2_6; bufA[4][tid] = y2_7; bufA[5][tid] = y2_8;
        __syncthreads();                              // [C2]

        // ---- step 3: rows L=3..8, horiz bufA[L-3] ----
        horiz(&bufA[0][0], tid, y2_3, &xl, &xr);
        float4 y3_3 = stepw(cw[2], (mb0 >> 3) & 1, (mb1 >> 3) & 1, y2_3, y2_2, y2_4, xl, xr);
        horiz(&bufA[1][0], tid, y2_4, &xl, &xr);
        float4 y3_4 = stepw(cw[3], (mb0 >> 4) & 1, (mb1 >> 4) & 1, y2_4, y2_3, y2_5, xl, xr);
        horiz(&bufA[2][0], tid, y2_5, &xl, &xr);
        float4 y3_5 = stepw(cw[4], (mb0 >> 5) & 1, (mb1 >> 5) & 1, y2_5, y2_4, y2_6, xl, xr);
        horiz(&bufA[3][0], tid, y2_6, &xl, &xr);
        float4 y3_6 = stepw(cw[5], (mb0 >> 6) & 1, (mb1 >> 6) & 1, y2_6, y2_5, y2_7, xl, xr);
        horiz(&bufA[4][0], tid, y2_7, &xl, &xr);
        float4 y3_7 = stepw(cw[6], (mb0 >> 7) & 1, (mb1 >> 7) & 1, y2_7, y2_6, y2_8, xl, xr);
        horiz(&bufA[5][0], tid, y2_8, &xl, &xr);
        float4 y3_8 = stepw(cw[7], (mb0 >> 8) & 1, (mb1 >> 8) & 1, y2_8, y2_7, y2_9, xl, xr);
        bufB[0][tid] = y3_4; bufB[1][tid] = y3_5;
        bufB[2][tid] = y3_6; bufB[3][tid] = y3_7;
        __syncthreads();                              // [C3]

        // ---- step 4: own rows L=4..7; publish each o row the moment it exists ----
        i32x2* pout = (m & 1) ? parE : parO;
        const bool last = (m == NSYNC - 1);

        horiz(&bufB[0][0], tid, y3_4, &xl, &xr);
        float4 o0 = stepw(cw[3], (mb0 >> 4) & 1, (mb1 >> 4) & 1, y3_4, y3_3, y3_5, xl, xr);
        if (!last) cst8(pout, (i0 + 0) * ROWP + tid, pack4(o0));
        horiz(&bufB[1][0], tid, y3_5, &xl, &xr);
        float4 o1 = stepw(cw[4], (mb0 >> 5) & 1, (mb1 >> 5) & 1, y3_5, y3_4, y3_6, xl, xr);
        if (!last) cst8(pout, (i0 + 1) * ROWP + tid, pack4(o1));
        horiz(&bufB[2][0], tid, y3_6, &xl, &xr);
        float4 o2 = stepw(cw[5], (mb0 >> 6) & 1, (mb1 >> 6) & 1, y3_6, y3_5, y3_7, xl, xr);
        if (!last) cst8(pout, (i0 + 2) * ROWP + tid, pack4(o2));
        horiz(&bufB[3][0], tid, y3_7, &xl, &xr);
        float4 o3 = stepw(cw[6], (mb0 >> 7) & 1, (mb1 >> 7) & 1, y3_7, y3_6, y3_8, xl, xr);
        if (!last) cst8(pout, (i0 + 3) * ROWP + tid, pack4(o3));

        if (last) {
            // x_100 -> d_out fp32 (never read by any block: race-free)
            out4[(i0 + 0) * ROWP + tid] = o0;
            out4[(i0 + 1) * ROWP + tid] = o1;
            out4[(i0 + 2) * ROWP + tid] = o2;
            out4[(i0 + 3) * ROWP + tid] = o3;
            break;
        }

        waitvm0();                                    // each wave drains publishes
        __syncthreads();                              // [D] all waves drained
        if (tid == 0)
            __hip_atomic_store(&flags[(m + 1) * NBLK + band], TOKEN,
                               __ATOMIC_RELAXED, __HIP_MEMORY_SCOPE_AGENT);

        // ---- off-chain: LDS writeback + register rotation (hidden under the
        // neighbors' poll window; made visible by next sync's [A] barrier) ----
        bufA[3][tid] = o0; bufA[4][tid] = o1;
        bufA[5][tid] = o2; bufA[6][tid] = o3;
        s0 = o0; s1 = o1; s2 = o2; s3 = o3;
    }
}

extern "C" void kernel_launch(void* const* d_in, const int* in_sizes, int n_in,
                              void* d_out, int out_size, void* d_ws, size_t ws_size,
                              hipStream_t stream) {
    const float* img = (const float*)d_in[0];
    const int* seeds = (const int*)d_in[1];

    float4* out4 = (float4*)d_out;                              // fp32 final only
    char* ws = (char*)d_ws;
    i32x2* parE = (i32x2*)ws;                                   // 4 MB fp16 even parity
    i32x2* parO = (i32x2*)(ws + 4ull * 1024 * 1024);            // 4 MB fp16 odd parity
    unsigned* flags = (unsigned*)(ws + 8ull * 1024 * 1024);     // 25.6 KB token slots

    rw_init_kernel<<<(FLAGS_N + 255) / 256, 256, 0, stream>>>(flags);
    rw_persist_kernel<<<NBLK, TPB, 0, stream>>>(img, seeds, out4, parE, parO, flags);
}

// Round 6
// 241.464 us; speedup vs baseline: 1.9381x; 1.5123x over previous
//
#include <hip/hip_runtime.h>
#include <hip/hip_fp16.h>

typedef __attribute__((ext_vector_type(2))) int i32x2;

#define HH 1024
#define ROWP 512                   // pixel-pairs per row
#define NBLK 256                   // 1 block/CU -> co-resident
#define TPB 512
#define NSYNC 50                   // 2 Jacobi steps per sync
#define BOUNDARY_F 0.1f
#define TOKEN 0x5A5A5A5Au
#define FLAGS_N (NSYNC * NBLK)

union h2u { __half2 h; int i; };

__device__ __forceinline__ i32x2 pack4(float4 v) {     // fp32x4 -> fp16x4 (RNE)
    h2u a, b;
    a.h = __float22half2_rn(make_float2(v.x, v.y));
    b.h = __float22half2_rn(make_float2(v.z, v.w));
    i32x2 r; r.x = a.i; r.y = b.i;
    return r;
}
__device__ __forceinline__ float4 unpack4(i32x2 p) {
    h2u a, b; a.i = p.x; b.i = p.y;
    float2 lo = __half22float2(a.h);
    float2 hi = __half22float2(b.h);
    return make_float4(lo.x, lo.y, hi.x, hi.y);
}

// coherent 8B store: single fabric transaction, bypasses non-coherent L2
__device__ __forceinline__ void cst8(i32x2* base, int elem, i32x2 val) {
    asm volatile("global_store_dwordx2 %0, %1, %2 sc0 sc1"
                 :: "v"(elem * 8), "v"(val), "s"(base) : "memory");
}
// coherent 8B load; result MUST be passed through wait4 before any use
__device__ __forceinline__ i32x2 cld8(const i32x2* base, int elem) {
    i32x2 t;
    asm volatile("global_load_dwordx2 %0, %1, %2 sc0 sc1"
                 : "=v"(t) : "v"(elem * 8), "s"(base) : "memory");
    return t;
}
// s_waitcnt with loaded registers as in/out operands: all later uses have a
// data dependency THROUGH the waitcnt (round-12-verified hazard fix).
__device__ __forceinline__ void wait4(i32x2& a, i32x2& b, i32x2& c, i32x2& d) {
    asm volatile("s_waitcnt vmcnt(0)"
                 : "+v"(a), "+v"(b), "+v"(c), "+v"(d) :: "memory");
}
__device__ __forceinline__ void waitvm0() {
    asm volatile("s_waitcnt vmcnt(0)" ::: "memory");
}

__device__ __forceinline__ float wfun(float c, float n, float valid) {
    float same = ((c > BOUNDARY_F) != (n > BOUNDARY_F)) ? 1.0f : 0.0f;
    return valid * __expf(-fabsf(c - n + same));
}

// Jacobi update of one pixel-pair; w = {w0u,w0d,w0l,w0r, w1u,w1d,w1l,w1r}
__device__ __forceinline__ float4 stepr(const float* w, bool m0, bool m1,
                                        float4 xc, float4 xu, float4 xd,
                                        float2 xl, float2 xr) {
    float4 o;
    o.x = w[0]*xu.x + w[1]*xd.x + w[2]*xl.x + w[3]*xc.z;
    o.y = w[0]*xu.y + w[1]*xd.y + w[2]*xl.y + w[3]*xc.w;
    o.z = w[4]*xu.z + w[5]*xd.z + w[6]*xc.x + w[7]*xr.x;
    o.w = w[4]*xu.w + w[5]*xd.w + w[6]*xc.y + w[7]*xr.y;
    if (m0) { o.x = xc.x; o.y = xc.y; }     // absorbing seeds
    if (m1) { o.z = xc.z; o.w = xc.w; }
    return o;
}

__device__ __forceinline__ void horiz(const float4* row, int tid, float4 xc,
                                      float2* xl, float2* xr) {
    const float2* r2 = (const float2*)row;
    *xl = (tid > 0) ? r2[2 * tid - 1] : make_float2(xc.x, xc.y);
    *xr = (tid < ROWP - 1) ? r2[2 * tid + 2] : make_float2(xc.z, xc.w);
}

// zero all flag slots: every launch self-contained (round-16-verified fix)
__global__ void rw_init_kernel(unsigned* __restrict__ flags) {
    int g = blockIdx.x * blockDim.x + threadIdx.x;
    if (g < FLAGS_N) flags[g] = 0u;
}

__launch_bounds__(TPB)
__global__ void rw_persist_kernel(const float* __restrict__ img,
                                  const int* __restrict__ seeds,
                                  float4* __restrict__ out4,   // d_out fp32, final only
                                  i32x2* __restrict__ parE,    // ws: fp16 x_{2m}, m even
                                  i32x2* __restrict__ parO,    // ws: fp16 x_{2m}, m odd
                                  unsigned* __restrict__ flags) {
    const int tid = threadIdx.x;
    const int blk = blockIdx.x;
    const int band = ((blk & 7) << 5) | (blk >> 3);   // XCD swizzle (perf only)
    const int i0 = band * 4;

    // slots 0..5: x rows i0-1..i0+4 (horizontal copies, fp32); 6..9: y rows
    __shared__ float4 srows[10][ROWP];                // 80 KB

    // ---- iteration-invariant weights + masks for rows i0-1..i0+4 ----
    float cfv[6][8];
    unsigned mb0 = 0, mb1 = 0;
    float4 s0, s1, s2, s3;                            // register-resident band (fp32)
    {
        const float2* img2 = (const float2*)img;
        const int2* seeds2 = (const int2*)seeds;
#pragma unroll
        for (int L = 0; L < 6; ++L) {
            const int g = min(max(i0 - 1 + L, 0), HH - 1);
            const int P = g * ROWP + tid;
            const int p = P * 2;
            const int j = p & 1023;
            const int uP = (g > 0) ? P - ROWP : P;
            const int dP = (g < HH - 1) ? P + ROWP : P;
            const int lp = (j > 0) ? p - 1 : p;
            const int rp = (j < 1022) ? p + 2 : p + 1;

            float2 cc = img2[P], iu = img2[uP], id = img2[dP];
            float il = img[lp], ir = img[rp];
            const float vU = (g > 0) ? 1.0f : 0.0f;
            const float vD = (g < HH - 1) ? 1.0f : 0.0f;
            const float vL = (j > 0) ? 1.0f : 0.0f;
            const float vR = (j < 1022) ? 1.0f : 0.0f;

            float w0u = wfun(cc.x, iu.x, vU), w0d = wfun(cc.x, id.x, vD);
            float w0l = wfun(cc.x, il, vL),   w0r = wfun(cc.x, cc.y, 1.0f);
            float rs0 = w0u + w0d + w0l + w0r;
            float inv0 = (rs0 > 0.0f) ? 1.0f / rs0 : 0.0f;
            float w1u = wfun(cc.y, iu.y, vU), w1d = wfun(cc.y, id.y, vD);
            float w1l = wfun(cc.y, cc.x, 1.0f), w1r = wfun(cc.y, ir, vR);
            float rs1 = w1u + w1d + w1l + w1r;
            float inv1 = (rs1 > 0.0f) ? 1.0f / rs1 : 0.0f;

            cfv[L][0] = w0u * inv0; cfv[L][1] = w0d * inv0;
            cfv[L][2] = w0l * inv0; cfv[L][3] = w0r * inv0;
            cfv[L][4] = w1u * inv1; cfv[L][5] = w1d * inv1;
            cfv[L][6] = w1l * inv1; cfv[L][7] = w1r * inv1;

            int2 s = seeds2[P];
            if (s.x > 0) mb0 |= 1u << L;
            if (s.y > 0) mb1 |= 1u << L;
            if (L >= 1 && L <= 4) {
                float4 v;
                v.x = (s.x == 1) ? 1.0f : 0.0f;
                v.y = (s.x == 2) ? 1.0f : 0.0f;
                v.z = (s.y == 1) ? 1.0f : 0.0f;
                v.w = (s.y == 2) ? 1.0f : 0.0f;
                if (L == 1) s0 = v; else if (L == 2) s1 = v;
                else if (L == 3) s2 = v; else s3 = v;
            }
        }
    }

    // ---- publish x0 (fp16) -> parE + seed LDS horizontal copies ----
    srows[1][tid] = s0; srows[2][tid] = s1;
    srows[3][tid] = s2; srows[4][tid] = s3;
    cst8(parE, (i0 + 0) * ROWP + tid, pack4(s0));
    cst8(parE, (i0 + 1) * ROWP + tid, pack4(s1));
    cst8(parE, (i0 + 2) * ROWP + tid, pack4(s2));
    cst8(parE, (i0 + 3) * ROWP + tid, pack4(s3));
    waitvm0();
    __syncthreads();               // LDS visible + publish drained
    if (tid == 0)
        __hip_atomic_store(&flags[band], TOKEN, __ATOMIC_RELAXED,
                           __HIP_MEMORY_SCOPE_AGENT);

    const int gU2 = max(i0 - 2, 0), gU1 = max(i0 - 1, 0);
    const int gD0 = min(i0 + 4, HH - 1), gD1 = min(i0 + 5, HH - 1);

    for (int m = 0; m < NSYNC; ++m) {
        // ---- poll neighbors' x_{2m} flags (two waves in parallel, no backoff:
        // poll period = natural ~L3 load latency; relaxed loads, no cache ops) ----
        if (tid == 0 && band > 0) {
            int guard = 0;
            while (__hip_atomic_load(&flags[m * NBLK + band - 1], __ATOMIC_RELAXED,
                                     __HIP_MEMORY_SCOPE_AGENT) != TOKEN) {
                if (++guard > (1 << 22)) break;
            }
        }
        if (tid == 64 && band < NBLK - 1) {
            int guard = 0;
            while (__hip_atomic_load(&flags[m * NBLK + band + 1], __ATOMIC_RELAXED,
                                     __HIP_MEMORY_SCOPE_AGENT) != TOKEN) {
                if (++guard > (1 << 22)) break;
            }
        }
        __syncthreads();                              // [A]
        asm volatile("" ::: "memory");

        const i32x2* pin = (m & 1) ? parO : parE;

        // ---- issue 2-deep ghost row loads (coherent fp16 8B) ----
        i32x2 rA = cld8(pin, gU2 * ROWP + tid);       // row i0-2
        i32x2 rB = cld8(pin, gU1 * ROWP + tid);       // row i0-1
        i32x2 rC = cld8(pin, gD0 * ROWP + tid);       // row i0+4
        i32x2 rD = cld8(pin, gD1 * ROWP + tid);       // row i0+5

        // ---- step 1 interior rows (no ghost dep) while loads fly ----
        float2 xl, xr;
        horiz(&srows[2][0], tid, s1, &xl, &xr);
        float4 y2 = stepr(cfv[2], (mb0 >> 2) & 1, (mb1 >> 2) & 1, s1, s0, s2, xl, xr);
        horiz(&srows[3][0], tid, s2, &xl, &xr);
        float4 y3 = stepr(cfv[3], (mb0 >> 3) & 1, (mb1 >> 3) & 1, s2, s1, s3, xl, xr);
        srows[7][tid] = y2;
        srows[8][tid] = y3;

        wait4(rA, rB, rC, rD);                        // loads landed; deps tied
        float4 vU2 = unpack4(rA);
        float4 vU1 = unpack4(rB);
        float4 vD0 = unpack4(rC);
        float4 vD1 = unpack4(rD);
        srows[0][tid] = vU1;
        srows[5][tid] = vD0;
        __syncthreads();                              // [B]

        // ---- step 1 ghost-dependent rows ----
        horiz(&srows[0][0], tid, vU1, &xl, &xr);
        float4 y0 = stepr(cfv[0], (mb0 >> 0) & 1, (mb1 >> 0) & 1, vU1, vU2, s0, xl, xr);
        horiz(&srows[1][0], tid, s0, &xl, &xr);
        float4 y1 = stepr(cfv[1], (mb0 >> 1) & 1, (mb1 >> 1) & 1, s0, vU1, s1, xl, xr);
        horiz(&srows[4][0], tid, s3, &xl, &xr);
        float4 y4 = stepr(cfv[4], (mb0 >> 4) & 1, (mb1 >> 4) & 1, s3, s2, vD0, xl, xr);
        horiz(&srows[5][0], tid, vD0, &xl, &xr);
        float4 y5 = stepr(cfv[5], (mb0 >> 5) & 1, (mb1 >> 5) & 1, vD0, s3, vD1, xl, xr);
        srows[6][tid] = y1;
        srows[9][tid] = y4;
        __syncthreads();                              // [C]

        // ---- step 2, own rows; publish each o row the moment it exists ----
        i32x2* pout = (m & 1) ? parE : parO;
        const bool last = (m == NSYNC - 1);

        horiz(&srows[6][0], tid, y1, &xl, &xr);
        float4 o0 = stepr(cfv[1], (mb0 >> 1) & 1, (mb1 >> 1) & 1, y1, y0, y2, xl, xr);
        if (!last) cst8(pout, (i0 + 0) * ROWP + tid, pack4(o0));
        horiz(&srows[7][0], tid, y2, &xl, &xr);
        float4 o1 = stepr(cfv[2], (mb0 >> 2) & 1, (mb1 >> 2) & 1, y2, y1, y3, xl, xr);
        if (!last) cst8(pout, (i0 + 1) * ROWP + tid, pack4(o1));
        horiz(&srows[8][0], tid, y3, &xl, &xr);
        float4 o2 = stepr(cfv[3], (mb0 >> 3) & 1, (mb1 >> 3) & 1, y3, y2, y4, xl, xr);
        if (!last) cst8(pout, (i0 + 2) * ROWP + tid, pack4(o2));
        horiz(&srows[9][0], tid, y4, &xl, &xr);
        float4 o3 = stepr(cfv[4], (mb0 >> 4) & 1, (mb1 >> 4) & 1, y4, y3, y5, xl, xr);
        if (!last) cst8(pout, (i0 + 3) * ROWP + tid, pack4(o3));

        if (last) {
            // x_100 -> d_out fp32 (never read by any block: race-free)
            out4[(i0 + 0) * ROWP + tid] = o0;
            out4[(i0 + 1) * ROWP + tid] = o1;
            out4[(i0 + 2) * ROWP + tid] = o2;
            out4[(i0 + 3) * ROWP + tid] = o3;
            break;
        }

        waitvm0();                                    // each wave drains publishes
        __syncthreads();                              // [D] all waves drained
        if (tid == 0)
            __hip_atomic_store(&flags[(m + 1) * NBLK + band], TOKEN,
                               __ATOMIC_RELAXED, __HIP_MEMORY_SCOPE_AGENT);

        // ---- off-chain: LDS writeback + register rotation (hidden under the
        // neighbors' poll window; made visible by next sync's [A] barrier) ----
        srows[1][tid] = o0; srows[2][tid] = o1;
        srows[3][tid] = o2; srows[4][tid] = o3;
        s0 = o0; s1 = o1; s2 = o2; s3 = o3;
    }
}

extern "C" void kernel_launch(void* const* d_in, const int* in_sizes, int n_in,
                              void* d_out, int out_size, void* d_ws, size_t ws_size,
                              hipStream_t stream) {
    const float* img = (const float*)d_in[0];
    const int* seeds = (const int*)d_in[1];

    float4* out4 = (float4*)d_out;                              // fp32 final only
    char* ws = (char*)d_ws;
    i32x2* parE = (i32x2*)ws;                                   // 4 MB fp16 even parity
    i32x2* parO = (i32x2*)(ws + 4ull * 1024 * 1024);            // 4 MB fp16 odd parity
    unsigned* flags = (unsigned*)(ws + 8ull * 1024 * 1024);     // 51.2 KB token slots

    rw_init_kernel<<<(FLAGS_N + 255) / 256, 256, 0, stream>>>(flags);
    rw_persist_kernel<<<NBLK, TPB, 0, stream>>>(img, seeds, out4, parE, parO, flags);
}